// Round 2
// baseline (159.159 us; speedup 1.0000x reference)
//
#include <hip/hip_runtime.h>
#include <math.h>

#define NN 8192
#define INF_ 128
#define OUTF 64

typedef __attribute__((ext_vector_type(4))) float f32x4;
typedef __attribute__((ext_vector_type(4))) int i32x4;
typedef __attribute__((ext_vector_type(8))) unsigned short u16x8;
typedef __attribute__((ext_vector_type(8))) __bf16 bf16x8;

__device__ __forceinline__ unsigned short f2bf(float f) {
    unsigned int u = __float_as_uint(f);
    u = (u + 0x7FFFu + ((u >> 16) & 1u)) >> 16;
    return (unsigned short)u;
}

// ---- Kernel 1: Wh = h@W (fp32); f1 = Wh@a1; f2 = Wh@a2; WhT = bf16(Wh)^T [64][8192]
__global__ __launch_bounds__(256) void prep_kernel(
    const float* __restrict__ h, const float* __restrict__ W,
    const float* __restrict__ a, unsigned short* __restrict__ WhT,
    float* __restrict__ f1, float* __restrict__ f2)
{
    __shared__ float W_lds[INF_ * OUTF];        // 32 KB [k][c]
    __shared__ float h_lds[32 * INF_];          // 16 KB [r][k]
    __shared__ unsigned short t_lds[OUTF * 34]; // transpose buffer, pad 34

    const int t = threadIdx.x;
    const int rb = blockIdx.x * 32;

    {
        const float4* Ws = (const float4*)W;
        float4* Wd = (float4*)W_lds;
        #pragma unroll
        for (int q = 0; q < 8; ++q) Wd[t + 256 * q] = Ws[t + 256 * q];
        const float4* hs = (const float4*)(h + (size_t)rb * INF_);
        float4* hd = (float4*)h_lds;
        #pragma unroll
        for (int q = 0; q < 4; ++q) hd[t + 256 * q] = hs[t + 256 * q];
    }
    __syncthreads();

    const int lane = t & 63;
    const int w = t >> 6;

    float acc[8];
    #pragma unroll
    for (int q = 0; q < 8; ++q) acc[q] = 0.f;
    for (int k = 0; k < INF_; ++k) {
        const float wv = W_lds[k * OUTF + lane];
        #pragma unroll
        for (int q = 0; q < 8; ++q)
            acc[q] = fmaf(h_lds[(w * 8 + q) * INF_ + k], wv, acc[q]);
    }

    const float a1 = a[lane];
    const float a2 = a[OUTF + lane];
    #pragma unroll
    for (int q = 0; q < 8; ++q) {
        float s1 = acc[q] * a1;
        float s2 = acc[q] * a2;
        #pragma unroll
        for (int m = 1; m < 64; m <<= 1) {
            s1 += __shfl_xor(s1, m, 64);
            s2 += __shfl_xor(s2, m, 64);
        }
        if (lane == 0) {
            f1[rb + w * 8 + q] = s1;
            f2[rb + w * 8 + q] = s2;
        }
        t_lds[lane * 34 + w * 8 + q] = f2bf(acc[q]);
    }
    __syncthreads();
    {
        const int c = t >> 2;
        const int ro = (t & 3) * 8;
        unsigned int pk[4];
        #pragma unroll
        for (int i = 0; i < 4; ++i) {
            const unsigned int lo = t_lds[c * 34 + ro + 2 * i];
            const unsigned int hi = t_lds[c * 34 + ro + 2 * i + 1];
            pk[i] = lo | (hi << 16);
        }
        *(uint4*)(WhT + (size_t)c * NN + rb + ro) = make_uint4(pk[0], pk[1], pk[2], pk[3]);
    }
}

// ---- Kernel 1b: f2max = max_j f2[j]
__global__ __launch_bounds__(256) void fmax_kernel(
    const float* __restrict__ f2, float* __restrict__ f2max)
{
    __shared__ float red[4];
    const int t = threadIdx.x;
    float m = -INFINITY;
    for (int i = t; i < NN; i += 256) m = fmaxf(m, f2[i]);
    #pragma unroll
    for (int s = 1; s < 64; s <<= 1) m = fmaxf(m, __shfl_xor(m, s, 64));
    if ((t & 63) == 0) red[t >> 6] = m;
    __syncthreads();
    if (t == 0) f2max[0] = fmaxf(fmaxf(red[0], red[1]), fmaxf(red[2], red[3]));
}

// ---- Kernel 2: fused masked-softmax(attention) @ Wh, static per-row max, one adj pass
#define WAVES 8
#define JW (NN / WAVES)   // 1024 j per wave
#define NCHUNK (JW / 32)  // 32 chunks of K=32

__global__ __launch_bounds__(512, 4) void gat_kernel(
    const int* __restrict__ adj, const unsigned short* __restrict__ WhT,
    const float* __restrict__ f1, const float* __restrict__ f2,
    const float* __restrict__ f2max, float* __restrict__ out)
{
    __shared__ float acc_lds[WAVES * 16 * OUTF]; // 32 KB
    __shared__ float l_lds[WAVES * 16];

    const int t = threadIdx.x;
    const int lane = t & 63;
    const int w = t >> 6;        // wave 0..7 -> j slice
    const int r = lane & 15;     // A-frag row (P row this lane generates)
    const int g = lane >> 4;     // k-group
    const int row_base = blockIdx.x * 16;

    const float f1r = f1[row_base + r];
    float Mr = f1r + f2max[0];
    Mr = fmaxf(Mr, 0.2f * Mr);   // leaky is monotone -> row-wise upper bound of e
    const int* adj_row = adj + (size_t)(row_base + r) * NN;
    const int j0 = w * JW;

    float l_run = 0.f;
    f32x4 acc0 = {0.f, 0.f, 0.f, 0.f};
    f32x4 acc1 = acc0, acc2 = acc0, acc3 = acc0;

    i32x4 ad0 = __builtin_nontemporal_load((const i32x4*)(adj_row + j0 + g * 8));
    i32x4 ad1 = __builtin_nontemporal_load((const i32x4*)(adj_row + j0 + g * 8 + 4));

    for (int c = 0; c < NCHUNK; ++c) {
        const int col = j0 + c * 32 + g * 8;
        const i32x4 c0 = ad0, c1 = ad1;
        if (c + 1 < NCHUNK) {
            ad0 = __builtin_nontemporal_load((const i32x4*)(adj_row + col + 32));
            ad1 = __builtin_nontemporal_load((const i32x4*)(adj_row + col + 36));
        }
        const float4 fa = *(const float4*)(f2 + col);
        const float4 fb = *(const float4*)(f2 + col + 4);

        float e[8];
        e[0] = f1r + fa.x; e[1] = f1r + fa.y; e[2] = f1r + fa.z; e[3] = f1r + fa.w;
        e[4] = f1r + fb.x; e[5] = f1r + fb.y; e[6] = f1r + fb.z; e[7] = f1r + fb.w;
        const int msk[8] = {c0[0], c0[1], c0[2], c0[3], c1[0], c1[1], c1[2], c1[3]};

        u16x8 pb;
        #pragma unroll
        for (int i = 0; i < 8; ++i) {
            const float le = fmaxf(e[i], 0.2f * e[i]);        // LeakyReLU
            float p = __expf(le - Mr);
            p = (msk[i] > 0) ? p : 0.f;
            const unsigned short b = f2bf(p);
            pb[i] = b;
            l_run += __uint_as_float(((unsigned int)b) << 16); // sum what MFMA consumes
        }

        const bf16x8 afrag = __builtin_bit_cast(bf16x8, pb);
        const unsigned short* bp = WhT + (size_t)r * NN + col;
        const bf16x8 b0 = __builtin_bit_cast(bf16x8, *(const u16x8*)(bp));
        const bf16x8 b1 = __builtin_bit_cast(bf16x8, *(const u16x8*)(bp + 16 * NN));
        const bf16x8 b2 = __builtin_bit_cast(bf16x8, *(const u16x8*)(bp + 32 * NN));
        const bf16x8 b3 = __builtin_bit_cast(bf16x8, *(const u16x8*)(bp + 48 * NN));
        acc0 = __builtin_amdgcn_mfma_f32_16x16x32_bf16(afrag, b0, acc0, 0, 0, 0);
        acc1 = __builtin_amdgcn_mfma_f32_16x16x32_bf16(afrag, b1, acc1, 0, 0, 0);
        acc2 = __builtin_amdgcn_mfma_f32_16x16x32_bf16(afrag, b2, acc2, 0, 0, 0);
        acc3 = __builtin_amdgcn_mfma_f32_16x16x32_bf16(afrag, b3, acc3, 0, 0, 0);
    }

    // row sum of P over this wave's slice (row r lives in lanes {r, r+16, r+32, r+48})
    l_run += __shfl_xor(l_run, 16, 64);
    l_run += __shfl_xor(l_run, 32, 64);
    if (lane < 16) l_lds[w * 16 + lane] = l_run;

    // D layout: col = lane&15 (= feature r), row = 4*g + q
    #pragma unroll
    for (int q = 0; q < 4; ++q) {
        const int m = 4 * g + q;
        float* dst = &acc_lds[(w * 16 + m) * OUTF + r];
        dst[0]  = acc0[q];
        dst[16] = acc1[q];
        dst[32] = acc2[q];
        dst[48] = acc3[q];
    }
    __syncthreads();

    {
        const int col = t & 63;
        const int row0 = t >> 6; // 0..7
        #pragma unroll
        for (int hh = 0; hh < 2; ++hh) {
            const int row = row0 + hh * 8;
            float L = 0.f, o = 0.f;
            #pragma unroll
            for (int ww = 0; ww < WAVES; ++ww) {
                L += l_lds[ww * 16 + row];
                o += acc_lds[(ww * 16 + row) * OUTF + col];
            }
            o /= L;
            o = (o > 0.f) ? o : expm1f(o); // ELU
            out[(size_t)(row_base + row) * OUTF + col] = o;
        }
    }
}

extern "C" void kernel_launch(void* const* d_in, const int* in_sizes, int n_in,
                              void* d_out, int out_size, void* d_ws, size_t ws_size,
                              hipStream_t stream) {
    const float* h = (const float*)d_in[0];
    const int* adj = (const int*)d_in[1];
    const float* W = (const float*)d_in[2];
    const float* a = (const float*)d_in[3];
    float* out = (float*)d_out;

    unsigned short* WhT = (unsigned short*)d_ws;                  // 64*8192*2 = 1 MB
    float* f1 = (float*)((char*)d_ws + (size_t)OUTF * NN * 2);    // 32 KB
    float* f2 = f1 + NN;                                          // 32 KB
    float* f2m = f2 + NN;                                         // 4 B

    prep_kernel<<<NN / 32, 256, 0, stream>>>(h, W, a, WhT, f1, f2);
    fmax_kernel<<<1, 256, 0, stream>>>(f2, f2m);
    gat_kernel<<<NN / 16, 512, 0, stream>>>(adj, WhT, f1, f2, f2m, out);
}

// Round 3
// 134.873 us; speedup vs baseline: 1.1801x; 1.1801x over previous
//
#include <hip/hip_runtime.h>
#include <hip/hip_bf16.h>
#include <math.h>

#define NN 8192
#define INF_ 128
#define OUTF 64

typedef __attribute__((ext_vector_type(4))) float f32x4;
typedef __attribute__((ext_vector_type(4))) int i32x4;
typedef __attribute__((ext_vector_type(8))) unsigned short u16x8;
typedef __attribute__((ext_vector_type(8))) __bf16 bf16x8;

__device__ __forceinline__ unsigned short f2bf(float f) {
    unsigned int u = __float_as_uint(f);
    u = (u + 0x7FFFu + ((u >> 16) & 1u)) >> 16;
    return (unsigned short)u;
}

// ---- Kernel 1: Wh = h@W (fp32); f1 = Wh@a1; f2 = Wh@a2; WhT = bf16(Wh)^T [64][8192]
__global__ __launch_bounds__(256) void prep_kernel(
    const float* __restrict__ h, const float* __restrict__ W,
    const float* __restrict__ a, unsigned short* __restrict__ WhT,
    float* __restrict__ f1, float* __restrict__ f2)
{
    __shared__ float W_lds[INF_ * OUTF];
    __shared__ float h_lds[32 * INF_];
    __shared__ unsigned short t_lds[OUTF * 34];

    const int t = threadIdx.x;
    const int rb = blockIdx.x * 32;

    {
        const float4* Ws = (const float4*)W;
        float4* Wd = (float4*)W_lds;
        #pragma unroll
        for (int q = 0; q < 8; ++q) Wd[t + 256 * q] = Ws[t + 256 * q];
        const float4* hs = (const float4*)(h + (size_t)rb * INF_);
        float4* hd = (float4*)h_lds;
        #pragma unroll
        for (int q = 0; q < 4; ++q) hd[t + 256 * q] = hs[t + 256 * q];
    }
    __syncthreads();

    const int lane = t & 63;
    const int w = t >> 6;

    float acc[8];
    #pragma unroll
    for (int q = 0; q < 8; ++q) acc[q] = 0.f;
    for (int k = 0; k < INF_; ++k) {
        const float wv = W_lds[k * OUTF + lane];
        #pragma unroll
        for (int q = 0; q < 8; ++q)
            acc[q] = fmaf(h_lds[(w * 8 + q) * INF_ + k], wv, acc[q]);
    }

    const float a1 = a[lane];
    const float a2 = a[OUTF + lane];
    #pragma unroll
    for (int q = 0; q < 8; ++q) {
        float s1 = acc[q] * a1;
        float s2 = acc[q] * a2;
        #pragma unroll
        for (int m = 1; m < 64; m <<= 1) {
            s1 += __shfl_xor(s1, m, 64);
            s2 += __shfl_xor(s2, m, 64);
        }
        if (lane == 0) {
            f1[rb + w * 8 + q] = s1;
            f2[rb + w * 8 + q] = s2;
        }
        t_lds[lane * 34 + w * 8 + q] = f2bf(acc[q]);
    }
    __syncthreads();
    {
        const int c = t >> 2;
        const int ro = (t & 3) * 8;
        unsigned int pk[4];
        #pragma unroll
        for (int i = 0; i < 4; ++i) {
            const unsigned int lo = t_lds[c * 34 + ro + 2 * i];
            const unsigned int hi = t_lds[c * 34 + ro + 2 * i + 1];
            pk[i] = lo | (hi << 16);
        }
        *(uint4*)(WhT + (size_t)c * NN + rb + ro) = make_uint4(pk[0], pk[1], pk[2], pk[3]);
    }
}

// ---- Kernel 1b: f2max = max_j f2[j]
__global__ __launch_bounds__(256) void fmax_kernel(
    const float* __restrict__ f2, float* __restrict__ f2max)
{
    __shared__ float red[4];
    const int t = threadIdx.x;
    float m = -INFINITY;
    for (int i = t; i < NN; i += 256) m = fmaxf(m, f2[i]);
    #pragma unroll
    for (int s = 1; s < 64; s <<= 1) m = fmaxf(m, __shfl_xor(m, s, 64));
    if ((t & 63) == 0) red[t >> 6] = m;
    __syncthreads();
    if (t == 0) f2max[0] = fmaxf(fmaxf(red[0], red[1]), fmaxf(red[2], red[3]));
}

// ---- Kernel 1c: bitpack adj -> 1 bit per entry, linear j order.
// Perfectly coalesced: each wave reads 1 KB contiguous from ONE row per step.
__global__ __launch_bounds__(256) void bitpack_kernel(
    const int* __restrict__ adj, unsigned char* __restrict__ bits)
{
    const int row = blockIdx.x;
    const int t = threadIdx.x;
    const int lane = t & 63;
    const int w = t >> 6;
    const int* src = adj + (size_t)row * NN + w * 2048;
    unsigned char* dst = bits + (size_t)row * (NN / 8) + w * 256;

    #pragma unroll
    for (int s = 0; s < 8; ++s) {
        const i32x4 v = __builtin_nontemporal_load((const i32x4*)(src + s * 256 + 4 * lane));
        const unsigned long long b0 = __ballot(v[0] > 0); // bit l <-> j 4l+0
        const unsigned long long b1 = __ballot(v[1] > 0);
        const unsigned long long b2 = __ballot(v[2] > 0);
        const unsigned long long b3 = __ballot(v[3] > 0);
        if (lane < 32) {
            const unsigned int sh = 2 * lane;
            unsigned int B =
                ((unsigned int)(b0 >> sh) & 1u)        |
                (((unsigned int)(b1 >> sh) & 1u) << 1) |
                (((unsigned int)(b2 >> sh) & 1u) << 2) |
                (((unsigned int)(b3 >> sh) & 1u) << 3) |
                (((unsigned int)(b0 >> (sh + 1)) & 1u) << 4) |
                (((unsigned int)(b1 >> (sh + 1)) & 1u) << 5) |
                (((unsigned int)(b2 >> (sh + 1)) & 1u) << 6) |
                (((unsigned int)(b3 >> (sh + 1)) & 1u) << 7);
            dst[s * 32 + lane] = (unsigned char)B;
        }
    }
}

// ---- Kernel 2: fused masked-softmax(attention) @ Wh; masks from bit array
#define WAVES 8
#define JW (NN / WAVES)   // 1024 j per wave
#define NCHUNK (JW / 32)  // 32 chunks of K=32

__global__ __launch_bounds__(512, 4) void gat_kernel(
    const unsigned char* __restrict__ bits, const unsigned short* __restrict__ WhT,
    const float* __restrict__ f1, const float* __restrict__ f2,
    const float* __restrict__ f2max, float* __restrict__ out)
{
    __shared__ float acc_lds[WAVES * 16 * OUTF]; // 32 KB
    __shared__ float l_lds[WAVES * 16];

    const int t = threadIdx.x;
    const int lane = t & 63;
    const int w = t >> 6;
    const int r = lane & 15;     // A-frag row / B-frag col
    const int g = lane >> 4;     // k-group
    const int row_base = blockIdx.x * 16;

    const float f1r = f1[row_base + r];
    float Mr = f1r + f2max[0];
    Mr = fmaxf(Mr, 0.2f * Mr);
    const float nML2E = -Mr * 1.44269504f;
    const int j0 = w * JW;
    const unsigned char* bitrow = bits + (size_t)(row_base + r) * (NN / 8) + (j0 >> 3);

    f32x4 acc0 = {0.f, 0.f, 0.f, 0.f};
    f32x4 acc1 = acc0, acc2 = acc0, acc3 = acc0, accl = acc0;

    u16x8 ones_u;
    #pragma unroll
    for (int i = 0; i < 8; ++i) ones_u[i] = 0x3F80;
    const bf16x8 bones = __builtin_bit_cast(bf16x8, ones_u);

    i32x4 mk = *(const i32x4*)(bitrow); // 16 B = masks for 4 chunks (128 j)

    for (int mg = 0; mg < NCHUNK / 4; ++mg) {
        const i32x4 mkc = mk;
        if (mg + 1 < NCHUNK / 4) mk = *(const i32x4*)(bitrow + (mg + 1) * 16);
        #pragma unroll
        for (int cc = 0; cc < 4; ++cc) {
            const int c = mg * 4 + cc;
            const int col = j0 + c * 32 + g * 8;
            const unsigned int mbyte = (((unsigned int)mkc[cc]) >> (8 * g)) & 0xFFu;
            const float4 fa = *(const float4*)(f2 + col);
            const float4 fb = *(const float4*)(f2 + col + 4);

            float e[8];
            e[0] = f1r + fa.x; e[1] = f1r + fa.y; e[2] = f1r + fa.z; e[3] = f1r + fa.w;
            e[4] = f1r + fb.x; e[5] = f1r + fb.y; e[6] = f1r + fb.z; e[7] = f1r + fb.w;

            u16x8 pb;
            #pragma unroll
            for (int i = 0; i < 8; ++i) {
                const float le = fmaxf(e[i], 0.2f * e[i]);               // LeakyReLU
                float p = exp2f(fmaf(le, 1.44269504f, nML2E));           // exp(le - Mr)
                p = ((mbyte >> i) & 1u) ? p : 0.f;
                pb[i] = __builtin_bit_cast(unsigned short, __float2bfloat16(p));
            }

            const bf16x8 afrag = __builtin_bit_cast(bf16x8, pb);
            const unsigned short* bp = WhT + (size_t)r * NN + col;
            const bf16x8 b0 = __builtin_bit_cast(bf16x8, *(const u16x8*)(bp));
            const bf16x8 b1 = __builtin_bit_cast(bf16x8, *(const u16x8*)(bp + 16 * NN));
            const bf16x8 b2 = __builtin_bit_cast(bf16x8, *(const u16x8*)(bp + 32 * NN));
            const bf16x8 b3 = __builtin_bit_cast(bf16x8, *(const u16x8*)(bp + 48 * NN));
            acc0 = __builtin_amdgcn_mfma_f32_16x16x32_bf16(afrag, b0, acc0, 0, 0, 0);
            acc1 = __builtin_amdgcn_mfma_f32_16x16x32_bf16(afrag, b1, acc1, 0, 0, 0);
            acc2 = __builtin_amdgcn_mfma_f32_16x16x32_bf16(afrag, b2, acc2, 0, 0, 0);
            acc3 = __builtin_amdgcn_mfma_f32_16x16x32_bf16(afrag, b3, acc3, 0, 0, 0);
            accl = __builtin_amdgcn_mfma_f32_16x16x32_bf16(afrag, bones, accl, 0, 0, 0);
        }
    }

    // D layout: col = lane&15, row = 4*g + q. accl holds row-sums (same for all cols).
    if (r == 0) {
        #pragma unroll
        for (int q = 0; q < 4; ++q) l_lds[w * 16 + 4 * g + q] = accl[q];
    }
    #pragma unroll
    for (int q = 0; q < 4; ++q) {
        const int m = 4 * g + q;
        float* dst = &acc_lds[(w * 16 + m) * OUTF + r];
        dst[0]  = acc0[q];
        dst[16] = acc1[q];
        dst[32] = acc2[q];
        dst[48] = acc3[q];
    }
    __syncthreads();

    {
        const int col = t & 63;
        const int row0 = t >> 6;
        #pragma unroll
        for (int hh = 0; hh < 2; ++hh) {
            const int row = row0 + hh * 8;
            float L = 0.f, o = 0.f;
            #pragma unroll
            for (int ww = 0; ww < WAVES; ++ww) {
                L += l_lds[ww * 16 + row];
                o += acc_lds[(ww * 16 + row) * OUTF + col];
            }
            o /= L;
            o = (o > 0.f) ? o : expm1f(o); // ELU
            out[(size_t)(row_base + row) * OUTF + col] = o;
        }
    }
}

extern "C" void kernel_launch(void* const* d_in, const int* in_sizes, int n_in,
                              void* d_out, int out_size, void* d_ws, size_t ws_size,
                              hipStream_t stream) {
    const float* h = (const float*)d_in[0];
    const int* adj = (const int*)d_in[1];
    const float* W = (const float*)d_in[2];
    const float* a = (const float*)d_in[3];
    float* out = (float*)d_out;

    char* ws = (char*)d_ws;
    unsigned short* WhT = (unsigned short*)ws;                     // 1 MB
    unsigned char* bits = (unsigned char*)(ws + (1 << 20));        // 8 MB
    float* f1 = (float*)(ws + (1 << 20) + (NN * (NN / 8)));        // 32 KB
    float* f2 = f1 + NN;                                           // 32 KB
    float* f2m = f2 + NN;                                          // 4 B

    prep_kernel<<<NN / 32, 256, 0, stream>>>(h, W, a, WhT, f1, f2);
    bitpack_kernel<<<NN, 256, 0, stream>>>(adj, bits);
    fmax_kernel<<<1, 256, 0, stream>>>(f2, f2m);
    gat_kernel<<<NN / 16, 512, 0, stream>>>(bits, WhT, f1, f2, f2m, out);
}

// Round 4
// 133.454 us; speedup vs baseline: 1.1926x; 1.0106x over previous
//
#include <hip/hip_runtime.h>
#include <hip/hip_bf16.h>
#include <math.h>

#define NN 8192
#define INF_ 128
#define OUTF 64

typedef __attribute__((ext_vector_type(4))) float f32x4;
typedef __attribute__((ext_vector_type(4))) int i32x4;
typedef __attribute__((ext_vector_type(8))) unsigned short u16x8;
typedef __attribute__((ext_vector_type(8))) __bf16 bf16x8;

__device__ __forceinline__ unsigned short f2bf(float f) {
    unsigned int u = __float_as_uint(f);
    u = (u + 0x7FFFu + ((u >> 16) & 1u)) >> 16;
    return (unsigned short)u;
}

// ---- Kernel 1: Wh = h@W (fp32); f1 = Wh@a1; f2 = Wh@a2; WhT = bf16(Wh)^T [64][8192]
__global__ __launch_bounds__(256) void prep_kernel(
    const float* __restrict__ h, const float* __restrict__ W,
    const float* __restrict__ a, unsigned short* __restrict__ WhT,
    float* __restrict__ f1, float* __restrict__ f2)
{
    __shared__ float W_lds[INF_ * OUTF];
    __shared__ float h_lds[32 * INF_];
    __shared__ unsigned short t_lds[OUTF * 34];

    const int t = threadIdx.x;
    const int rb = blockIdx.x * 32;

    {
        const float4* Ws = (const float4*)W;
        float4* Wd = (float4*)W_lds;
        #pragma unroll
        for (int q = 0; q < 8; ++q) Wd[t + 256 * q] = Ws[t + 256 * q];
        const float4* hs = (const float4*)(h + (size_t)rb * INF_);
        float4* hd = (float4*)h_lds;
        #pragma unroll
        for (int q = 0; q < 4; ++q) hd[t + 256 * q] = hs[t + 256 * q];
    }
    __syncthreads();

    const int lane = t & 63;
    const int w = t >> 6;

    float acc[8];
    #pragma unroll
    for (int q = 0; q < 8; ++q) acc[q] = 0.f;
    for (int k = 0; k < INF_; ++k) {
        const float wv = W_lds[k * OUTF + lane];
        #pragma unroll
        for (int q = 0; q < 8; ++q)
            acc[q] = fmaf(h_lds[(w * 8 + q) * INF_ + k], wv, acc[q]);
    }

    const float a1 = a[lane];
    const float a2 = a[OUTF + lane];
    #pragma unroll
    for (int q = 0; q < 8; ++q) {
        float s1 = acc[q] * a1;
        float s2 = acc[q] * a2;
        #pragma unroll
        for (int m = 1; m < 64; m <<= 1) {
            s1 += __shfl_xor(s1, m, 64);
            s2 += __shfl_xor(s2, m, 64);
        }
        if (lane == 0) {
            f1[rb + w * 8 + q] = s1;
            f2[rb + w * 8 + q] = s2;
        }
        t_lds[lane * 34 + w * 8 + q] = f2bf(acc[q]);
    }
    __syncthreads();
    {
        const int c = t >> 2;
        const int ro = (t & 3) * 8;
        unsigned int pk[4];
        #pragma unroll
        for (int i = 0; i < 4; ++i) {
            const unsigned int lo = t_lds[c * 34 + ro + 2 * i];
            const unsigned int hi = t_lds[c * 34 + ro + 2 * i + 1];
            pk[i] = lo | (hi << 16);
        }
        *(uint4*)(WhT + (size_t)c * NN + rb + ro) = make_uint4(pk[0], pk[1], pk[2], pk[3]);
    }
}

// ---- Kernel 1b: f2max = max_j f2[j]
__global__ __launch_bounds__(1024) void fmax_kernel(
    const float* __restrict__ f2, float* __restrict__ f2max)
{
    __shared__ float red[16];
    const int t = threadIdx.x;
    float m = -INFINITY;
    #pragma unroll
    for (int q = 0; q < NN / 1024; ++q) m = fmaxf(m, f2[t + q * 1024]);
    #pragma unroll
    for (int s = 1; s < 64; s <<= 1) m = fmaxf(m, __shfl_xor(m, s, 64));
    if ((t & 63) == 0) red[t >> 6] = m;
    __syncthreads();
    if (t == 0) {
        float r = red[0];
        #pragma unroll
        for (int i = 1; i < 16; ++i) r = fmaxf(r, red[i]);
        f2max[0] = r;
    }
}

// ---- Kernel 2: fully fused: coalesced adj stream -> ballot bitmask (LDS) ->
//      masked softmax (static per-row max) -> PV via MFMA. adj read ONCE.
#define WAVES 8
#define JW (NN / WAVES)     // 1024 j per wave
#define NGRP (JW / 256)     // 4 groups of 256 j
#define MROWB 36            // padded bytes per row in mask buffer (bank-conflict-free reads)

__global__ __launch_bounds__(512) void gat_kernel(
    const int* __restrict__ adj, const unsigned short* __restrict__ WhT,
    const float* __restrict__ f1, const float* __restrict__ f2,
    const float* __restrict__ f2max, float* __restrict__ out)
{
    __shared__ float acc_lds[WAVES * 16 * OUTF];            // 32 KB
    __shared__ float l_lds[WAVES * 16];
    __shared__ unsigned char mask_lds[WAVES * 16 * MROWB];  // 4.6 KB

    const int t = threadIdx.x;
    const int lane = t & 63;
    const int w = t >> 6;
    const int r = lane & 15;     // A-frag row / B-frag col
    const int g = lane >> 4;     // k-group
    const int row_base = blockIdx.x * 16;

    const float f1r = f1[row_base + r];
    float Mr = f1r + f2max[0];
    Mr = fmaxf(Mr, 0.2f * Mr);
    const float nML2E = -Mr * 1.44269504f;
    const int j0 = w * JW;
    const int* adj_base = adj + (size_t)row_base * NN + j0;
    unsigned char* mbuf = mask_lds + w * 16 * MROWB;

    f32x4 acc0 = {0.f, 0.f, 0.f, 0.f};
    f32x4 acc1 = acc0, acc2 = acc0, acc3 = acc0, accl = acc0;

    u16x8 ones_u;
    #pragma unroll
    for (int i = 0; i < 8; ++i) ones_u[i] = 0x3F80;
    const bf16x8 bones = __builtin_bit_cast(bf16x8, ones_u);

    // stage group 0: one coalesced 1 KB load per row (16 rows x 256 ints)
    i32x4 st[16];
    #pragma unroll
    for (int rr = 0; rr < 16; ++rr)
        st[rr] = __builtin_nontemporal_load((const i32x4*)(adj_base + (size_t)rr * NN + 4 * lane));

    for (int grp = 0; grp < NGRP; ++grp) {
        // -- produce mask bytes for this group (ballot transpose, r3-verified mapping)
        #pragma unroll
        for (int rr = 0; rr < 16; ++rr) {
            const i32x4 v = st[rr];
            const unsigned long long b0 = __ballot(v[0] > 0); // bit l <-> j 4l+0
            const unsigned long long b1 = __ballot(v[1] > 0);
            const unsigned long long b2 = __ballot(v[2] > 0);
            const unsigned long long b3 = __ballot(v[3] > 0);
            if (lane < 32) {
                const unsigned int sh = 2 * lane;
                unsigned int B =
                    ((unsigned int)(b0 >> sh) & 1u)        |
                    (((unsigned int)(b1 >> sh) & 1u) << 1) |
                    (((unsigned int)(b2 >> sh) & 1u) << 2) |
                    (((unsigned int)(b3 >> sh) & 1u) << 3) |
                    (((unsigned int)(b0 >> (sh + 1)) & 1u) << 4) |
                    (((unsigned int)(b1 >> (sh + 1)) & 1u) << 5) |
                    (((unsigned int)(b2 >> (sh + 1)) & 1u) << 6) |
                    (((unsigned int)(b3 >> (sh + 1)) & 1u) << 7);
                mbuf[rr * MROWB + lane] = (unsigned char)B; // byte l covers j [8l,8l+8)
            }
        }
        // -- issue next group's loads (latency hidden under consume phase)
        if (grp + 1 < NGRP) {
            #pragma unroll
            for (int rr = 0; rr < 16; ++rr)
                st[rr] = __builtin_nontemporal_load(
                    (const i32x4*)(adj_base + (size_t)rr * NN + (grp + 1) * 256 + 4 * lane));
        }
        // -- consume 8 chunks of 32 j
        #pragma unroll
        for (int cc = 0; cc < 8; ++cc) {
            const int col = j0 + grp * 256 + cc * 32 + g * 8;
            const unsigned int mbyte = mbuf[r * MROWB + cc * 4 + g];
            const float4 fa = *(const float4*)(f2 + col);
            const float4 fb = *(const float4*)(f2 + col + 4);

            float e[8];
            e[0] = f1r + fa.x; e[1] = f1r + fa.y; e[2] = f1r + fa.z; e[3] = f1r + fa.w;
            e[4] = f1r + fb.x; e[5] = f1r + fb.y; e[6] = f1r + fb.z; e[7] = f1r + fb.w;

            u16x8 pb;
            #pragma unroll
            for (int i = 0; i < 8; ++i) {
                const float le = fmaxf(e[i], 0.2f * e[i]);      // LeakyReLU
                float p = exp2f(fmaf(le, 1.44269504f, nML2E));  // exp(le - Mr)
                p = ((mbyte >> i) & 1u) ? p : 0.f;
                pb[i] = __builtin_bit_cast(unsigned short, __float2bfloat16(p));
            }

            const bf16x8 afrag = __builtin_bit_cast(bf16x8, pb);
            const unsigned short* bp = WhT + (size_t)r * NN + col;
            const bf16x8 b0 = __builtin_bit_cast(bf16x8, *(const u16x8*)(bp));
            const bf16x8 b1 = __builtin_bit_cast(bf16x8, *(const u16x8*)(bp + 16 * NN));
            const bf16x8 b2 = __builtin_bit_cast(bf16x8, *(const u16x8*)(bp + 32 * NN));
            const bf16x8 b3 = __builtin_bit_cast(bf16x8, *(const u16x8*)(bp + 48 * NN));
            acc0 = __builtin_amdgcn_mfma_f32_16x16x32_bf16(afrag, b0, acc0, 0, 0, 0);
            acc1 = __builtin_amdgcn_mfma_f32_16x16x32_bf16(afrag, b1, acc1, 0, 0, 0);
            acc2 = __builtin_amdgcn_mfma_f32_16x16x32_bf16(afrag, b2, acc2, 0, 0, 0);
            acc3 = __builtin_amdgcn_mfma_f32_16x16x32_bf16(afrag, b3, acc3, 0, 0, 0);
            accl = __builtin_amdgcn_mfma_f32_16x16x32_bf16(afrag, bones, accl, 0, 0, 0);
        }
    }

    // D layout: col = lane&15, row = 4*g + q. accl holds row-sums (same for all cols).
    if (r == 0) {
        #pragma unroll
        for (int q = 0; q < 4; ++q) l_lds[w * 16 + 4 * g + q] = accl[q];
    }
    #pragma unroll
    for (int q = 0; q < 4; ++q) {
        const int m = 4 * g + q;
        float* dst = &acc_lds[(w * 16 + m) * OUTF + r];
        dst[0]  = acc0[q];
        dst[16] = acc1[q];
        dst[32] = acc2[q];
        dst[48] = acc3[q];
    }
    __syncthreads();

    {
        const int col = t & 63;
        const int row0 = t >> 6;
        #pragma unroll
        for (int hh = 0; hh < 2; ++hh) {
            const int row = row0 + hh * 8;
            float L = 0.f, o = 0.f;
            #pragma unroll
            for (int ww = 0; ww < WAVES; ++ww) {
                L += l_lds[ww * 16 + row];
                o += acc_lds[(ww * 16 + row) * OUTF + col];
            }
            o /= L;
            o = (o > 0.f) ? o : expm1f(o); // ELU
            out[(size_t)(row_base + row) * OUTF + col] = o;
        }
    }
}

extern "C" void kernel_launch(void* const* d_in, const int* in_sizes, int n_in,
                              void* d_out, int out_size, void* d_ws, size_t ws_size,
                              hipStream_t stream) {
    const float* h = (const float*)d_in[0];
    const int* adj = (const int*)d_in[1];
    const float* W = (const float*)d_in[2];
    const float* a = (const float*)d_in[3];
    float* out = (float*)d_out;

    char* ws = (char*)d_ws;
    unsigned short* WhT = (unsigned short*)ws;              // 1 MB
    float* f1 = (float*)(ws + (1 << 20));                   // 32 KB
    float* f2 = f1 + NN;                                    // 32 KB
    float* f2m = f2 + NN;                                   // 4 B

    prep_kernel<<<NN / 32, 256, 0, stream>>>(h, W, a, WhT, f1, f2);
    fmax_kernel<<<1, 1024, 0, stream>>>(f2, f2m);
    gat_kernel<<<NN / 16, 512, 0, stream>>>(adj, WhT, f1, f2, f2m, out);
}

// Round 5
// 115.876 us; speedup vs baseline: 1.3735x; 1.1517x over previous
//
#include <hip/hip_runtime.h>
#include <hip/hip_bf16.h>
#include <math.h>

#define NN 8192
#define INF_ 128
#define OUTF 64

typedef __attribute__((ext_vector_type(4))) float f32x4;
typedef __attribute__((ext_vector_type(4))) int i32x4;
typedef __attribute__((ext_vector_type(8))) unsigned short u16x8;
typedef __attribute__((ext_vector_type(8))) __bf16 bf16x8;

__device__ __forceinline__ unsigned short f2bf(float f) {
    unsigned int u = __float_as_uint(f);
    u = (u + 0x7FFFu + ((u >> 16) & 1u)) >> 16;
    return (unsigned short)u;
}

// ---- Kernel 1: Wh = h@W (fp32); f1 = Wh@a1; f2 = Wh@a2; WhT = bf16(Wh)^T [64][8192]
__global__ __launch_bounds__(256) void prep_kernel(
    const float* __restrict__ h, const float* __restrict__ W,
    const float* __restrict__ a, unsigned short* __restrict__ WhT,
    float* __restrict__ f1, float* __restrict__ f2)
{
    __shared__ float W_lds[INF_ * OUTF];
    __shared__ float h_lds[32 * INF_];
    __shared__ unsigned short t_lds[OUTF * 34];

    const int t = threadIdx.x;
    const int rb = blockIdx.x * 32;

    {
        const float4* Ws = (const float4*)W;
        float4* Wd = (float4*)W_lds;
        #pragma unroll
        for (int q = 0; q < 8; ++q) Wd[t + 256 * q] = Ws[t + 256 * q];
        const float4* hs = (const float4*)(h + (size_t)rb * INF_);
        float4* hd = (float4*)h_lds;
        #pragma unroll
        for (int q = 0; q < 4; ++q) hd[t + 256 * q] = hs[t + 256 * q];
    }
    __syncthreads();

    const int lane = t & 63;
    const int w = t >> 6;

    float acc[8];
    #pragma unroll
    for (int q = 0; q < 8; ++q) acc[q] = 0.f;
    for (int k = 0; k < INF_; ++k) {
        const float wv = W_lds[k * OUTF + lane];
        #pragma unroll
        for (int q = 0; q < 8; ++q)
            acc[q] = fmaf(h_lds[(w * 8 + q) * INF_ + k], wv, acc[q]);
    }

    const float a1 = a[lane];
    const float a2 = a[OUTF + lane];
    #pragma unroll
    for (int q = 0; q < 8; ++q) {
        float s1 = acc[q] * a1;
        float s2 = acc[q] * a2;
        #pragma unroll
        for (int m = 1; m < 64; m <<= 1) {
            s1 += __shfl_xor(s1, m, 64);
            s2 += __shfl_xor(s2, m, 64);
        }
        if (lane == 0) {
            f1[rb + w * 8 + q] = s1;
            f2[rb + w * 8 + q] = s2;
        }
        t_lds[lane * 34 + w * 8 + q] = f2bf(acc[q]);
    }
    __syncthreads();
    {
        const int c = t >> 2;
        const int ro = (t & 3) * 8;
        unsigned int pk[4];
        #pragma unroll
        for (int i = 0; i < 4; ++i) {
            const unsigned int lo = t_lds[c * 34 + ro + 2 * i];
            const unsigned int hi = t_lds[c * 34 + ro + 2 * i + 1];
            pk[i] = lo | (hi << 16);
        }
        *(uint4*)(WhT + (size_t)c * NN + rb + ro) = make_uint4(pk[0], pk[1], pk[2], pk[3]);
    }
}

// ---- Kernel 1b: f2max = max_j f2[j]
__global__ __launch_bounds__(1024) void fmax_kernel(
    const float* __restrict__ f2, float* __restrict__ f2max)
{
    __shared__ float red[16];
    const int t = threadIdx.x;
    float m = -INFINITY;
    #pragma unroll
    for (int q = 0; q < NN / 1024; ++q) m = fmaxf(m, f2[t + q * 1024]);
    #pragma unroll
    for (int s = 1; s < 64; s <<= 1) m = fmaxf(m, __shfl_xor(m, s, 64));
    if ((t & 63) == 0) red[t >> 6] = m;
    __syncthreads();
    if (t == 0) {
        float r = red[0];
        #pragma unroll
        for (int i = 1; i < 16; ++i) r = fmaxf(r, red[i]);
        f2max[0] = r;
    }
}

// ---- Kernel 2: fully fused: coalesced adj stream (PLAIN cached loads) ->
//      ballot bitmask (LDS) -> masked softmax (static per-row max) -> PV via MFMA.
#define WAVES 8
#define JW (NN / WAVES)     // 1024 j per wave
#define NGRP (JW / 256)     // 4 groups of 256 j
#define MROWB 36            // padded bytes per row in mask buffer

__global__ __launch_bounds__(512) void gat_kernel(
    const int* __restrict__ adj, const unsigned short* __restrict__ WhT,
    const float* __restrict__ f1, const float* __restrict__ f2,
    const float* __restrict__ f2max, float* __restrict__ out)
{
    __shared__ float acc_lds[WAVES * 16 * OUTF];            // 32 KB
    __shared__ float l_lds[WAVES * 16];
    __shared__ unsigned char mask_lds[WAVES * 16 * MROWB];  // 4.6 KB

    const int t = threadIdx.x;
    const int lane = t & 63;
    const int w = t >> 6;
    const int r = lane & 15;     // A-frag row / B-frag col
    const int g = lane >> 4;     // k-group
    const int row_base = blockIdx.x * 16;

    const float f1r = f1[row_base + r];
    float Mr = f1r + f2max[0];
    Mr = fmaxf(Mr, 0.2f * Mr);
    const float nML2E = -Mr * 1.44269504f;
    const int j0 = w * JW;
    const int* adj_base = adj + (size_t)row_base * NN + j0;
    unsigned char* mbuf = mask_lds + w * 16 * MROWB;

    f32x4 acc0 = {0.f, 0.f, 0.f, 0.f};
    f32x4 acc1 = acc0, acc2 = acc0, acc3 = acc0, accl = acc0;

    u16x8 ones_u;
    #pragma unroll
    for (int i = 0; i < 8; ++i) ones_u[i] = 0x3F80;
    const bf16x8 bones = __builtin_bit_cast(bf16x8, ones_u);

    // stage group 0: one coalesced 1 KB load per row (16 rows x 256 ints)
    i32x4 st[16];
    #pragma unroll
    for (int rr = 0; rr < 16; ++rr)
        st[rr] = *(const i32x4*)(adj_base + (size_t)rr * NN + 4 * lane);

    for (int grp = 0; grp < NGRP; ++grp) {
        // -- produce mask bytes for this group (ballot transpose, r3-verified mapping)
        #pragma unroll
        for (int rr = 0; rr < 16; ++rr) {
            const i32x4 v = st[rr];
            const unsigned long long b0 = __ballot(v[0] > 0); // bit l <-> j 4l+0
            const unsigned long long b1 = __ballot(v[1] > 0);
            const unsigned long long b2 = __ballot(v[2] > 0);
            const unsigned long long b3 = __ballot(v[3] > 0);
            if (lane < 32) {
                const unsigned int sh = 2 * lane;
                unsigned int B =
                    ((unsigned int)(b0 >> sh) & 1u)        |
                    (((unsigned int)(b1 >> sh) & 1u) << 1) |
                    (((unsigned int)(b2 >> sh) & 1u) << 2) |
                    (((unsigned int)(b3 >> sh) & 1u) << 3) |
                    (((unsigned int)(b0 >> (sh + 1)) & 1u) << 4) |
                    (((unsigned int)(b1 >> (sh + 1)) & 1u) << 5) |
                    (((unsigned int)(b2 >> (sh + 1)) & 1u) << 6) |
                    (((unsigned int)(b3 >> (sh + 1)) & 1u) << 7);
                mbuf[rr * MROWB + lane] = (unsigned char)B; // byte l covers j [8l,8l+8)
            }
        }
        // -- issue next group's loads (latency hidden under consume phase)
        if (grp + 1 < NGRP) {
            #pragma unroll
            for (int rr = 0; rr < 16; ++rr)
                st[rr] = *(const i32x4*)(adj_base + (size_t)rr * NN + (grp + 1) * 256 + 4 * lane);
        }
        // -- consume 8 chunks of 32 j
        #pragma unroll
        for (int cc = 0; cc < 8; ++cc) {
            const int col = j0 + grp * 256 + cc * 32 + g * 8;
            const unsigned int mbyte = mbuf[r * MROWB + cc * 4 + g];
            const float4 fa = *(const float4*)(f2 + col);
            const float4 fb = *(const float4*)(f2 + col + 4);

            float e[8];
            e[0] = f1r + fa.x; e[1] = f1r + fa.y; e[2] = f1r + fa.z; e[3] = f1r + fa.w;
            e[4] = f1r + fb.x; e[5] = f1r + fb.y; e[6] = f1r + fb.z; e[7] = f1r + fb.w;

            u16x8 pb;
            #pragma unroll
            for (int i = 0; i < 8; ++i) {
                const float le = fmaxf(e[i], 0.2f * e[i]);      // LeakyReLU
                float p = exp2f(fmaf(le, 1.44269504f, nML2E));  // exp(le - Mr)
                p = ((mbyte >> i) & 1u) ? p : 0.f;
                pb[i] = __builtin_bit_cast(unsigned short, __float2bfloat16(p));
            }

            const bf16x8 afrag = __builtin_bit_cast(bf16x8, pb);
            const unsigned short* bp = WhT + (size_t)r * NN + col;
            const bf16x8 b0 = __builtin_bit_cast(bf16x8, *(const u16x8*)(bp));
            const bf16x8 b1 = __builtin_bit_cast(bf16x8, *(const u16x8*)(bp + 16 * NN));
            const bf16x8 b2 = __builtin_bit_cast(bf16x8, *(const u16x8*)(bp + 32 * NN));
            const bf16x8 b3 = __builtin_bit_cast(bf16x8, *(const u16x8*)(bp + 48 * NN));
            acc0 = __builtin_amdgcn_mfma_f32_16x16x32_bf16(afrag, b0, acc0, 0, 0, 0);
            acc1 = __builtin_amdgcn_mfma_f32_16x16x32_bf16(afrag, b1, acc1, 0, 0, 0);
            acc2 = __builtin_amdgcn_mfma_f32_16x16x32_bf16(afrag, b2, acc2, 0, 0, 0);
            acc3 = __builtin_amdgcn_mfma_f32_16x16x32_bf16(afrag, b3, acc3, 0, 0, 0);
            accl = __builtin_amdgcn_mfma_f32_16x16x32_bf16(afrag, bones, accl, 0, 0, 0);
        }
    }

    // D layout: col = lane&15, row = 4*g + q. accl holds row-sums (same for all cols).
    if (r == 0) {
        #pragma unroll
        for (int q = 0; q < 4; ++q) l_lds[w * 16 + 4 * g + q] = accl[q];
    }
    #pragma unroll
    for (int q = 0; q < 4; ++q) {
        const int m = 4 * g + q;
        float* dst = &acc_lds[(w * 16 + m) * OUTF + r];
        dst[0]  = acc0[q];
        dst[16] = acc1[q];
        dst[32] = acc2[q];
        dst[48] = acc3[q];
    }
    __syncthreads();

    {
        const int col = t & 63;
        const int row0 = t >> 6;
        #pragma unroll
        for (int hh = 0; hh < 2; ++hh) {
            const int row = row0 + hh * 8;
            float L = 0.f, o = 0.f;
            #pragma unroll
            for (int ww = 0; ww < WAVES; ++ww) {
                L += l_lds[ww * 16 + row];
                o += acc_lds[(ww * 16 + row) * OUTF + col];
            }
            o /= L;
            o = (o > 0.f) ? o : expm1f(o); // ELU
            out[(size_t)(row_base + row) * OUTF + col] = o;
        }
    }
}

extern "C" void kernel_launch(void* const* d_in, const int* in_sizes, int n_in,
                              void* d_out, int out_size, void* d_ws, size_t ws_size,
                              hipStream_t stream) {
    const float* h = (const float*)d_in[0];
    const int* adj = (const int*)d_in[1];
    const float* W = (const float*)d_in[2];
    const float* a = (const float*)d_in[3];
    float* out = (float*)d_out;

    char* ws = (char*)d_ws;
    unsigned short* WhT = (unsigned short*)ws;              // 1 MB
    float* f1 = (float*)(ws + (1 << 20));                   // 32 KB
    float* f2 = f1 + NN;                                    // 32 KB
    float* f2m = f2 + NN;                                   // 4 B

    prep_kernel<<<NN / 32, 256, 0, stream>>>(h, W, a, WhT, f1, f2);
    fmax_kernel<<<1, 1024, 0, stream>>>(f2, f2m);
    gat_kernel<<<NN / 16, 512, 0, stream>>>(adj, WhT, f1, f2, f2m, out);
}

// Round 6
// 111.702 us; speedup vs baseline: 1.4248x; 1.0374x over previous
//
#include <hip/hip_runtime.h>
#include <hip/hip_bf16.h>
#include <math.h>

#define NN 8192
#define INF_ 128
#define OUTF 64

typedef __attribute__((ext_vector_type(4))) float f32x4;
typedef __attribute__((ext_vector_type(4))) int i32x4;
typedef __attribute__((ext_vector_type(8))) unsigned short u16x8;
typedef __attribute__((ext_vector_type(8))) __bf16 bf16x8;

__device__ __forceinline__ unsigned short f2bf(float f) {
    unsigned int u = __float_as_uint(f);
    u = (u + 0x7FFFu + ((u >> 16) & 1u)) >> 16;
    return (unsigned short)u;
}

// ---- Kernel 1: Wh = h@W (fp32); f1 = Wh@a1; f2 = Wh@a2; WhT = bf16(Wh)^T [64][8192]
__global__ __launch_bounds__(256) void prep_kernel(
    const float* __restrict__ h, const float* __restrict__ W,
    const float* __restrict__ a, unsigned short* __restrict__ WhT,
    float* __restrict__ f1, float* __restrict__ f2)
{
    __shared__ float W_lds[INF_ * OUTF];
    __shared__ float h_lds[32 * INF_];
    __shared__ unsigned short t_lds[OUTF * 34];

    const int t = threadIdx.x;
    const int rb = blockIdx.x * 32;

    {
        const float4* Ws = (const float4*)W;
        float4* Wd = (float4*)W_lds;
        #pragma unroll
        for (int q = 0; q < 8; ++q) Wd[t + 256 * q] = Ws[t + 256 * q];
        const float4* hs = (const float4*)(h + (size_t)rb * INF_);
        float4* hd = (float4*)h_lds;
        #pragma unroll
        for (int q = 0; q < 4; ++q) hd[t + 256 * q] = hs[t + 256 * q];
    }
    __syncthreads();

    const int lane = t & 63;
    const int w = t >> 6;

    float acc[8];
    #pragma unroll
    for (int q = 0; q < 8; ++q) acc[q] = 0.f;
    for (int k = 0; k < INF_; ++k) {
        const float wv = W_lds[k * OUTF + lane];
        #pragma unroll
        for (int q = 0; q < 8; ++q)
            acc[q] = fmaf(h_lds[(w * 8 + q) * INF_ + k], wv, acc[q]);
    }

    const float a1 = a[lane];
    const float a2 = a[OUTF + lane];
    #pragma unroll
    for (int q = 0; q < 8; ++q) {
        float s1 = acc[q] * a1;
        float s2 = acc[q] * a2;
        #pragma unroll
        for (int m = 1; m < 64; m <<= 1) {
            s1 += __shfl_xor(s1, m, 64);
            s2 += __shfl_xor(s2, m, 64);
        }
        if (lane == 0) {
            f1[rb + w * 8 + q] = s1;
            f2[rb + w * 8 + q] = s2;
        }
        t_lds[lane * 34 + w * 8 + q] = f2bf(acc[q]);
    }
    __syncthreads();
    {
        const int c = t >> 2;
        const int ro = (t & 3) * 8;
        unsigned int pk[4];
        #pragma unroll
        for (int i = 0; i < 4; ++i) {
            const unsigned int lo = t_lds[c * 34 + ro + 2 * i];
            const unsigned int hi = t_lds[c * 34 + ro + 2 * i + 1];
            pk[i] = lo | (hi << 16);
        }
        *(uint4*)(WhT + (size_t)c * NN + rb + ro) = make_uint4(pk[0], pk[1], pk[2], pk[3]);
    }
}

// ---- Kernel 1b: f2max = max_j f2[j]
__global__ __launch_bounds__(1024) void fmax_kernel(
    const float* __restrict__ f2, float* __restrict__ f2max)
{
    __shared__ float red[16];
    const int t = threadIdx.x;
    float m = -INFINITY;
    #pragma unroll
    for (int q = 0; q < NN / 1024; ++q) m = fmaxf(m, f2[t + q * 1024]);
    #pragma unroll
    for (int s = 1; s < 64; s <<= 1) m = fmaxf(m, __shfl_xor(m, s, 64));
    if ((t & 63) == 0) red[t >> 6] = m;
    __syncthreads();
    if (t == 0) {
        float r = red[0];
        #pragma unroll
        for (int i = 1; i < 16; ++i) r = fmaxf(r, red[i]);
        f2max[0] = r;
    }
}

// ---- Kernel 1c: bitpack adj -> 1 bit per entry (PLAIN cached loads, pure stream)
__global__ __launch_bounds__(256) void bitpack_kernel(
    const int* __restrict__ adj, unsigned char* __restrict__ bits)
{
    const int row = blockIdx.x;
    const int t = threadIdx.x;
    const int lane = t & 63;
    const int w = t >> 6;
    const int* src = adj + (size_t)row * NN + w * 2048;
    unsigned char* dst = bits + (size_t)row * (NN / 8) + w * 256;

    #pragma unroll
    for (int s = 0; s < 8; ++s) {
        const i32x4 v = *(const i32x4*)(src + s * 256 + 4 * lane);
        const unsigned long long b0 = __ballot(v[0] > 0); // bit l <-> j 4l+0
        const unsigned long long b1 = __ballot(v[1] > 0);
        const unsigned long long b2 = __ballot(v[2] > 0);
        const unsigned long long b3 = __ballot(v[3] > 0);
        if (lane < 32) {
            const unsigned int sh = 2 * lane;
            unsigned int B =
                ((unsigned int)(b0 >> sh) & 1u)        |
                (((unsigned int)(b1 >> sh) & 1u) << 1) |
                (((unsigned int)(b2 >> sh) & 1u) << 2) |
                (((unsigned int)(b3 >> sh) & 1u) << 3) |
                (((unsigned int)(b0 >> (sh + 1)) & 1u) << 4) |
                (((unsigned int)(b1 >> (sh + 1)) & 1u) << 5) |
                (((unsigned int)(b2 >> (sh + 1)) & 1u) << 6) |
                (((unsigned int)(b3 >> (sh + 1)) & 1u) << 7);
            dst[s * 32 + lane] = (unsigned char)B; // byte l covers j [8l,8l+8)
        }
    }
}

// ---- Kernel 2: consumer. 32 rows/block (WhT B-frags reused by 2 A-frags).
//      All loads are L2/L3-resident (bits, f2, WhT). No HBM in the loop.
#define CW 8
#define CJW (NN / CW)     // 1024 j per wave
#define CMG (CJW / 128)   // 8 megagroups of 128 j (4 chunks)

__global__ __launch_bounds__(512) void gat2_kernel(
    const unsigned char* __restrict__ bits, const unsigned short* __restrict__ WhT,
    const float* __restrict__ f1, const float* __restrict__ f2,
    const float* __restrict__ f2max, float* __restrict__ out)
{
    __shared__ float acc_lds[CW * 32 * OUTF]; // 64 KB
    __shared__ float l_lds[CW * 32];

    const int t = threadIdx.x;
    const int lane = t & 63;
    const int w = t >> 6;
    const int r = lane & 15;     // A-frag row within tile / B-frag feature
    const int g = lane >> 4;     // k-group
    const int row_base = blockIdx.x * 32;

    const float f2m = f2max[0];
    const float f1r0 = f1[row_base + r];
    const float f1r1 = f1[row_base + 16 + r];
    float Mr0 = f1r0 + f2m; Mr0 = fmaxf(Mr0, 0.2f * Mr0);
    float Mr1 = f1r1 + f2m; Mr1 = fmaxf(Mr1, 0.2f * Mr1);
    const float nM0 = -Mr0 * 1.44269504f;
    const float nM1 = -Mr1 * 1.44269504f;

    const int j0 = w * CJW;
    const unsigned char* bitrow0 = bits + (size_t)(row_base + r) * (NN / 8) + (j0 >> 3);
    const unsigned char* bitrow1 = bits + (size_t)(row_base + 16 + r) * (NN / 8) + (j0 >> 3);

    f32x4 a0[4], a1[4], al0 = {0.f, 0.f, 0.f, 0.f}, al1 = {0.f, 0.f, 0.f, 0.f};
    #pragma unroll
    for (int q = 0; q < 4; ++q) { a0[q] = al0; a1[q] = al0; }

    u16x8 ones_u;
    #pragma unroll
    for (int i = 0; i < 8; ++i) ones_u[i] = 0x3F80;
    const bf16x8 bones = __builtin_bit_cast(bf16x8, ones_u);

    for (int mg = 0; mg < CMG; ++mg) {
        const i32x4 mk0 = *(const i32x4*)(bitrow0 + mg * 16); // 4 chunks' masks, row tile0
        const i32x4 mk1 = *(const i32x4*)(bitrow1 + mg * 16); // row tile1
        #pragma unroll
        for (int cc = 0; cc < 4; ++cc) {
            const int col = j0 + mg * 128 + cc * 32 + g * 8;
            const unsigned int mb0 = (((unsigned int)mk0[cc]) >> (8 * g)) & 0xFFu;
            const unsigned int mb1 = (((unsigned int)mk1[cc]) >> (8 * g)) & 0xFFu;
            const float4 fa = *(const float4*)(f2 + col);
            const float4 fb = *(const float4*)(f2 + col + 4);
            const float f2v[8] = {fa.x, fa.y, fa.z, fa.w, fb.x, fb.y, fb.z, fb.w};

            u16x8 pb0, pb1;
            #pragma unroll
            for (int i = 0; i < 8; ++i) {
                const float e0 = f1r0 + f2v[i];
                const float e1 = f1r1 + f2v[i];
                const float le0 = fmaxf(e0, 0.2f * e0);
                const float le1 = fmaxf(e1, 0.2f * e1);
                float p0 = exp2f(fmaf(le0, 1.44269504f, nM0));
                float p1 = exp2f(fmaf(le1, 1.44269504f, nM1));
                p0 = ((mb0 >> i) & 1u) ? p0 : 0.f;
                p1 = ((mb1 >> i) & 1u) ? p1 : 0.f;
                pb0[i] = __builtin_bit_cast(unsigned short, __float2bfloat16(p0));
                pb1[i] = __builtin_bit_cast(unsigned short, __float2bfloat16(p1));
            }

            const bf16x8 af0 = __builtin_bit_cast(bf16x8, pb0);
            const bf16x8 af1 = __builtin_bit_cast(bf16x8, pb1);
            const unsigned short* bp = WhT + (size_t)r * NN + col;
            #pragma unroll
            for (int qd = 0; qd < 4; ++qd) {
                const bf16x8 bq = __builtin_bit_cast(bf16x8, *(const u16x8*)(bp + qd * 16 * NN));
                a0[qd] = __builtin_amdgcn_mfma_f32_16x16x32_bf16(af0, bq, a0[qd], 0, 0, 0);
                a1[qd] = __builtin_amdgcn_mfma_f32_16x16x32_bf16(af1, bq, a1[qd], 0, 0, 0);
            }
            al0 = __builtin_amdgcn_mfma_f32_16x16x32_bf16(af0, bones, al0, 0, 0, 0);
            al1 = __builtin_amdgcn_mfma_f32_16x16x32_bf16(af1, bones, al1, 0, 0, 0);
        }
    }

    // D layout: col(lane&15)=feature r, row = 4*g + q (within 16-row tile)
    if (r == 0) {
        #pragma unroll
        for (int q = 0; q < 4; ++q) {
            l_lds[w * 32 + 4 * g + q]      = al0[q];
            l_lds[w * 32 + 16 + 4 * g + q] = al1[q];
        }
    }
    #pragma unroll
    for (int q = 0; q < 4; ++q) {
        const int m = 4 * g + q;
        #pragma unroll
        for (int qd = 0; qd < 4; ++qd) {
            acc_lds[(w * 32 + m) * OUTF + qd * 16 + r]      = a0[qd][q];
            acc_lds[(w * 32 + 16 + m) * OUTF + qd * 16 + r] = a1[qd][q];
        }
    }
    __syncthreads();

    {
        const int col = t & 63;
        const int row0 = t >> 6;
        #pragma unroll
        for (int hh = 0; hh < 4; ++hh) {
            const int row = row0 + hh * 8;
            float L = 0.f, o = 0.f;
            #pragma unroll
            for (int ww = 0; ww < CW; ++ww) {
                L += l_lds[ww * 32 + row];
                o += acc_lds[(ww * 32 + row) * OUTF + col];
            }
            o /= L;
            o = (o > 0.f) ? o : expm1f(o); // ELU
            out[(size_t)(row_base + row) * OUTF + col] = o;
        }
    }
}

extern "C" void kernel_launch(void* const* d_in, const int* in_sizes, int n_in,
                              void* d_out, int out_size, void* d_ws, size_t ws_size,
                              hipStream_t stream) {
    const float* h = (const float*)d_in[0];
    const int* adj = (const int*)d_in[1];
    const float* W = (const float*)d_in[2];
    const float* a = (const float*)d_in[3];
    float* out = (float*)d_out;

    char* ws = (char*)d_ws;
    unsigned short* WhT = (unsigned short*)ws;                  // 1 MB
    unsigned char* bits = (unsigned char*)(ws + (1 << 20));     // 8 MB
    float* f1 = (float*)(ws + (1 << 20) + NN * (NN / 8));       // 32 KB
    float* f2 = f1 + NN;                                        // 32 KB
    float* f2m = f2 + NN;                                       // 4 B

    prep_kernel<<<NN / 32, 256, 0, stream>>>(h, W, a, WhT, f1, f2);
    fmax_kernel<<<1, 1024, 0, stream>>>(f2, f2m);
    bitpack_kernel<<<NN, 256, 0, stream>>>(adj, bits);
    gat2_kernel<<<NN / 32, 512, 0, stream>>>(bits, WhT, f1, f2, f2m, out);
}